// Round 3
// baseline (166.023 us; speedup 1.0000x reference)
//
#include <hip/hip_runtime.h>
#include <math.h>

#define B_TOT 16384
#define H     128
#define NC    10
#define NATT  3
#define TR    16      // rows per block; 8 waves split the 128 cols (16 each)
#define HBS   136     // bf16 LDS row stride in ushorts (272B, 16B-aligned)
#define KT    5       // degree-4 minimax of exp on [-1,1]; max err ~5.9e-4
#define EPS   1e-5f
#define EXM_CS 196    // exm copy stride (floats): 196%32=4 -> 8 copies on disjoint bank quads
#define EXL_CS 34     // exl copy stride (floats): 34%32=2

typedef __attribute__((ext_vector_type(8))) short bf16x8;
typedef __attribute__((ext_vector_type(4))) float f32x4;

__device__ __forceinline__ ushort f2bf(float f) {
    union { float f; unsigned u; } v; v.f = f;
    unsigned r = v.u + 0x7fffu + ((v.u >> 16) & 1u);   // RNE
    return (ushort)(r >> 16);
}

// tanh(a) = 1 - 2/(e^{2a}+1); saturates correctly for |a| large
__device__ __forceinline__ float fast_tanh(float a) {
    float t = __expf(2.f * a);
    return 1.f - 2.f * __builtin_amdgcn_rcpf(t + 1.f);
}

template<int CTRL>
__device__ __forceinline__ float dpp_add(float v) {
    int x = __float_as_int(v);
    int y = __builtin_amdgcn_update_dpp(0, x, CTRL, 0xf, 0xf, false);
    return v + __int_as_float(y);
}
// all-reduce over the 16 lanes of a DPP row
__device__ __forceinline__ float red16(float v) {
    v = dpp_add<0x121>(v);   // row_ror:1
    v = dpp_add<0x122>(v);   // row_ror:2
    v = dpp_add<0x124>(v);   // row_ror:4
    v = dpp_add<0x128>(v);   // row_ror:8
    return v;
}
// sum of 8 consecutive lanes (mod 16): with lane s reading LDS copy (s&7),
// this sums all 8 wave copies exactly once.
__device__ __forceinline__ float red8ror(float v) {
    v = dpp_add<0x121>(v);   // row_ror:1
    v = dpp_add<0x122>(v);   // row_ror:2
    v = dpp_add<0x124>(v);   // row_ror:4
    return v;
}

// ---- prep: wt[mat][n][k]; mat0=W_in^T, mat1..3=W_att^T, mat4=W_c^T padded to 16 rows ----
extern "C" __global__ __launch_bounds__(256)
void prep_weights(const float* __restrict__ W_in,
                  const float* __restrict__ W_att,
                  const float* __restrict__ W_c,
                  ushort* __restrict__ wt)
{
    int i = blockIdx.x * 256 + threadIdx.x;
    if (i < 65536) {
        int mat = i >> 14, idx = i & 16383;
        int k = idx >> 7, n = idx & 127;
        float v = (mat == 0) ? W_in[idx] : W_att[(mat - 1) * 16384 + idx];
        wt[mat * 16384 + n * H + k] = f2bf(v);
    } else if (i < 65536 + 2048) {
        int idx = i - 65536;
        int n = idx >> 7, k = idx & 127;
        float v = (n < NC) ? W_c[k * NC + n] : 0.f;
        wt[65536 + n * H + k] = f2bf(v);
    }
}

extern "C" __global__ __launch_bounds__(512, 8)
void simple_attention_kernel(const float* __restrict__ x,
                             const float* __restrict__ b_in,
                             const float* __restrict__ b_att,
                             const float* __restrict__ gamma,
                             const float* __restrict__ beta,
                             const float* __restrict__ b_c,
                             const ushort* __restrict__ wt,
                             float* __restrict__ out)
{
    __shared__ __align__(16) ushort ab[TR * HBS];       // bf16 A-tile (shared by 8 waves)
    __shared__ __align__(16) float  exm[8 * EXM_CS];    // moment exchange: 9 vals/row/copy
    __shared__ __align__(16) float  exl[8 * EXL_CS];    // LN exchange

    const int tid  = threadIdx.x;
    const int wv   = tid >> 6;          // wave 0..7 owns cols [16wv, 16wv+16)
    const int lane = tid & 63;
    const int s    = lane & 15;
    const int q    = lane >> 4;
    const size_t rowBase = (size_t)blockIdx.x * TR;
    const int colN = 16 * wv + s;       // this lane's column

    float h[4];        // h[r]: row 4q+r, col colN
    f32x4 acc;

    // ---- stage x tile to LDS as bf16 (waves 0..3 convert 32-col slices) ----
    if (wv < 4) {
        const float* xp = x + (rowBase + s) * H + 32 * wv + q * 8;
        float4 v0 = *(const float4*)xp;
        float4 v1 = *(const float4*)(xp + 4);
        bf16x8 a;
        a[0] = f2bf(v0.x); a[1] = f2bf(v0.y); a[2] = f2bf(v0.z); a[3] = f2bf(v0.w);
        a[4] = f2bf(v1.x); a[5] = f2bf(v1.y); a[6] = f2bf(v1.z); a[7] = f2bf(v1.w);
        *(bf16x8*)&ab[s * HBS + 32 * wv + q * 8] = a;
    }
    __syncthreads();

    // ---- in_proj GEMM: each wave 16 rows x 16 cols (one MFMA tile) ----
    {
        bf16x8 af[4];
        #pragma unroll
        for (int ks = 0; ks < 4; ++ks)
            af[ks] = *(const bf16x8*)&ab[s * HBS + ks * 32 + q * 8];
        acc = (f32x4){0.f, 0.f, 0.f, 0.f};
        #pragma unroll
        for (int ks = 0; ks < 4; ++ks) {
            bf16x8 b = *(const bf16x8*)&wt[colN * H + ks * 32 + q * 8];
            acc = __builtin_amdgcn_mfma_f32_16x16x32_bf16(af[ks], b, acc, 0, 0, 0);
        }
        __syncthreads();   // all x-tile reads complete before h overwrites ab
        float bi = b_in[colN];
        #pragma unroll
        for (int r = 0; r < 4; ++r) {
            h[r] = acc[r] + bi;
            ab[(4 * q + r) * HBS + colN] = f2bf(h[r]);
        }
        __syncthreads();
    }

    // degree-4 Chebyshev-truncated minimax of e^v on [-1,1]
    const float cm[KT] = {1.00004478f, 0.99730768f, 0.49919676f, 0.17734736f, 0.04379392f};

    #pragma unroll 1
    for (int layer = 0; layer < NATT; ++layer) {
        const ushort* WT = wt + (size_t)(1 + layer) * 16384;

        // ---- phase A: u = tanh(h @ W + b) ----
        bf16x8 af[4];
        #pragma unroll
        for (int ks = 0; ks < 4; ++ks)
            af[ks] = *(const bf16x8*)&ab[s * HBS + ks * 32 + q * 8];
        acc = (f32x4){0.f, 0.f, 0.f, 0.f};
        #pragma unroll
        for (int ks = 0; ks < 4; ++ks) {
            bf16x8 b = *(const bf16x8*)&WT[colN * H + ks * 32 + q * 8];
            acc = __builtin_amdgcn_mfma_f32_16x16x32_bf16(af[ks], b, acc, 0, 0, 0);
        }
        float ba = b_att[layer * H + colN];
        float u[4];
        #pragma unroll
        for (int r = 0; r < 4; ++r) u[r] = fast_tanh(acc[r] + ba);

        // ---- raw moments (single col per lane: direct products, no accumulation) ----
        float S[4][KT], T[4][KT - 1];
        #pragma unroll
        for (int r = 0; r < 4; ++r) {
            float uu = u[r], hh = h[r];
            S[r][0] = hh;
            float p = uu;
            S[r][1] = p * hh; T[r][0] = p;
            #pragma unroll
            for (int k = 2; k < KT; ++k) {
                p *= uu;
                S[r][k] = p * hh;
                T[r][k - 1] = p;
            }
        }
        #pragma unroll
        for (int r = 0; r < 4; ++r) {
            #pragma unroll
            for (int k = 0; k < KT; ++k)     S[r][k] = red16(S[r][k]);
            #pragma unroll
            for (int k = 0; k < KT - 1; ++k) T[r][k] = red16(T[r][k]);
        }
        if (s == 0) {
            #pragma unroll
            for (int r = 0; r < 4; ++r) {
                float* dst = &exm[wv * EXM_CS + (4 * q + r) * 12];
                *(f32x4*)&dst[0] = (f32x4){S[r][0], S[r][1], S[r][2], S[r][3]};
                *(f32x4*)&dst[4] = (f32x4){S[r][4], T[r][0], T[r][1], T[r][2]};
                dst[8] = T[r][3];
            }
        }
        __syncthreads();
        // lane-distributed combine: lane s reads copy (s&7); ror:1+2+4 sums all 8
        #pragma unroll
        for (int r = 0; r < 4; ++r) {
            const float* src = &exm[(s & 7) * EXM_CS + (4 * q + r) * 12];
            f32x4 c0 = *(const f32x4*)&src[0];
            f32x4 c1 = *(const f32x4*)&src[4];
            float c2 = src[8];
            S[r][0] = red8ror(c0.x) * cm[0];
            S[r][1] = red8ror(c0.y) * cm[1];
            S[r][2] = red8ror(c0.z) * cm[2];
            S[r][3] = red8ror(c0.w) * cm[3];
            S[r][4] = red8ror(c1.x) * cm[4];
            T[r][0] = red8ror(c1.y) * cm[1];
            T[r][1] = red8ror(c1.z) * cm[2];
            T[r][2] = red8ror(c1.w) * cm[3];
            T[r][3] = red8ror(c2)   * cm[4];
        }

        // ---- Horner + residual ----
        #pragma unroll
        for (int r = 0; r < 4; ++r) {
            float uu = u[r];
            float num = S[r][KT - 1];
            #pragma unroll
            for (int k = KT - 2; k >= 0; --k) num = num * uu + S[r][k];
            float den = T[r][KT - 2];
            #pragma unroll
            for (int k = KT - 3; k >= 0; --k) den = den * uu + T[r][k];
            den = den * uu + 128.f * 1.00004478f;   // c0 * T0
            h[r] = h[r] + num * __builtin_amdgcn_rcpf(den);
        }

        // ---- LN partials (single col: partial IS y, y^2) ----
        float lsv[4], lqv[4];
        #pragma unroll
        for (int r = 0; r < 4; ++r) {
            lsv[r] = red16(h[r]);
            lqv[r] = red16(h[r] * h[r]);
        }
        if (s == 0) {
            #pragma unroll
            for (int r = 0; r < 4; ++r)
                *(float2*)&exl[wv * EXL_CS + (4 * q + r) * 2] = make_float2(lsv[r], lqv[r]);
        }
        __syncthreads();
        // ---- LN epilogue: normalize + refresh shared bf16 tile ----
        float g  = gamma[layer * H + colN];
        float be = beta [layer * H + colN];
        #pragma unroll
        for (int r = 0; r < 4; ++r) {
            float2 o = *(const float2*)&exl[(s & 7) * EXL_CS + (4 * q + r) * 2];
            float sm = red8ror(o.x), sq = red8ror(o.y);
            float mu = sm * (1.f / H);
            float var = sq * (1.f / H) - mu * mu;
            float inv = rsqrtf(var + EPS);
            float hn = (h[r] - mu) * inv * g + be;
            h[r] = hn;
            ab[(4 * q + r) * HBS + colN] = f2bf(hn);
        }
        __syncthreads();
    }

    // ---- final proj: wave 0 computes 16 rows x NC via one MFMA tile ----
    if (wv == 0) {
        const ushort* WC = wt + 4 * 16384;
        f32x4 facc = (f32x4){0.f, 0.f, 0.f, 0.f};
        #pragma unroll
        for (int ks = 0; ks < 4; ++ks) {
            bf16x8 a = *(const bf16x8*)&ab[s * HBS + ks * 32 + q * 8];
            bf16x8 b = *(const bf16x8*)&WC[s * H + ks * 32 + q * 8];
            facc = __builtin_amdgcn_mfma_f32_16x16x32_bf16(a, b, facc, 0, 0, 0);
        }
        if (s < NC) {
            float bc = b_c[s];
            #pragma unroll
            for (int r = 0; r < 4; ++r)
                out[(rowBase + 4 * q + r) * NC + s] = facc[r] + bc;
        }
    }
}

extern "C" void kernel_launch(void* const* d_in, const int* in_sizes, int n_in,
                              void* d_out, int out_size, void* d_ws, size_t ws_size,
                              hipStream_t stream) {
    const float* x     = (const float*)d_in[0];
    const float* W_in  = (const float*)d_in[1];
    const float* b_in  = (const float*)d_in[2];
    const float* W_att = (const float*)d_in[3];
    const float* b_att = (const float*)d_in[4];
    const float* gamma = (const float*)d_in[5];
    const float* beta  = (const float*)d_in[6];
    const float* W_c   = (const float*)d_in[7];
    const float* b_c   = (const float*)d_in[8];
    float* out  = (float*)d_out;
    ushort* wt  = (ushort*)d_ws;    // 5 mats: 4*16384 + 2048 ushorts = 136 KiB

    hipLaunchKernelGGL(prep_weights, dim3(264), dim3(256), 0, stream,
                       W_in, W_att, W_c, wt);
    hipLaunchKernelGGL(simple_attention_kernel, dim3(B_TOT / TR), dim3(512), 0, stream,
                       x, b_in, b_att, gamma, beta, b_c, wt, out);
}

// Round 5
// 114.100 us; speedup vs baseline: 1.4551x; 1.4551x over previous
//
#include <hip/hip_runtime.h>
#include <math.h>

#define B_TOT 16384
#define H     128
#define NC    10
#define NATT  3
#define TR    16      // rows per block; 8 waves split the 128 cols (16 each)
#define HBS   136     // bf16 LDS row stride in ushorts (272B, 16B-aligned)
#define KT    5       // degree-4 minimax of exp on [-1,1]; max err ~5.9e-4
#define EPS   1e-5f
#define EXM_CS 196    // exm copy stride (floats): 196%32=4 -> copies on rotating bank quads
#define EXL_CS 34     // exl copy stride (floats): 34%32=2

typedef __attribute__((ext_vector_type(8))) short bf16x8;
typedef __attribute__((ext_vector_type(4))) float f32x4;

__device__ __forceinline__ ushort f2bf(float f) {
    union { float f; unsigned u; } v; v.f = f;
    unsigned r = v.u + 0x7fffu + ((v.u >> 16) & 1u);   // RNE
    return (ushort)(r >> 16);
}

// tanh(a) = 1 - 2/(e^{2a}+1); saturates correctly for |a| large
__device__ __forceinline__ float fast_tanh(float a) {
    float t = __expf(2.f * a);
    return 1.f - 2.f * __builtin_amdgcn_rcpf(t + 1.f);
}

template<int CTRL>
__device__ __forceinline__ float dpp_add(float v) {
    int x = __float_as_int(v);
    int y = __builtin_amdgcn_update_dpp(0, x, CTRL, 0xf, 0xf, false);
    return v + __int_as_float(y);
}
// all-reduce over the 16 lanes of a DPP row
__device__ __forceinline__ float red16(float v) {
    v = dpp_add<0x121>(v);   // row_ror:1
    v = dpp_add<0x122>(v);   // row_ror:2
    v = dpp_add<0x124>(v);   // row_ror:4
    v = dpp_add<0x128>(v);   // row_ror:8
    return v;
}
// sum of 8 consecutive lanes (mod 16): with lane s reading LDS copy (s&7),
// this sums all 8 wave copies exactly once.
__device__ __forceinline__ float red8ror(float v) {
    v = dpp_add<0x121>(v);   // row_ror:1
    v = dpp_add<0x122>(v);   // row_ror:2
    v = dpp_add<0x124>(v);   // row_ror:4
    return v;
}

// ---- prep: wt[mat][n][k]; mat0=W_in^T, mat1..3=W_att^T, mat4=W_c^T padded to 16 rows ----
extern "C" __global__ __launch_bounds__(256)
void prep_weights(const float* __restrict__ W_in,
                  const float* __restrict__ W_att,
                  const float* __restrict__ W_c,
                  ushort* __restrict__ wt)
{
    int i = blockIdx.x * 256 + threadIdx.x;
    if (i < 65536) {
        int mat = i >> 14, idx = i & 16383;
        int k = idx >> 7, n = idx & 127;
        float v = (mat == 0) ? W_in[idx] : W_att[(mat - 1) * 16384 + idx];
        wt[mat * 16384 + n * H + k] = f2bf(v);
    } else if (i < 65536 + 2048) {
        int idx = i - 65536;
        int n = idx >> 7, k = idx & 127;
        float v = (n < NC) ? W_c[k * NC + n] : 0.f;
        wt[65536 + n * H + k] = f2bf(v);
    }
}

extern "C" __global__ __launch_bounds__(512, 6)
void simple_attention_kernel(const float* __restrict__ x,
                             const float* __restrict__ b_in,
                             const float* __restrict__ b_att,
                             const float* __restrict__ gamma,
                             const float* __restrict__ beta,
                             const float* __restrict__ b_c,
                             const ushort* __restrict__ wt,
                             float* __restrict__ out)
{
    __shared__ __align__(16) ushort ab[TR * HBS];       // bf16 A-tile (shared by 8 waves)
    __shared__ __align__(16) float  exm[8 * EXM_CS];    // moment exchange: 9 vals/row/copy
    __shared__ __align__(16) float  exl[8 * EXL_CS];    // LN exchange

    const int tid  = threadIdx.x;
    const int wv   = tid >> 6;          // wave 0..7 owns cols [16wv, 16wv+16)
    const int lane = tid & 63;
    const int s    = lane & 15;
    const int q    = lane >> 4;
    const size_t rowBase = (size_t)blockIdx.x * TR;
    const int colN = 16 * wv + s;       // this lane's column

    float h[4];        // h[r]: row 4q+r, col colN
    f32x4 acc;

    // ---- stage x tile to LDS as bf16 (waves 0..3 convert 32-col slices) ----
    if (wv < 4) {
        const float* xp = x + (rowBase + s) * H + 32 * wv + q * 8;
        float4 v0 = *(const float4*)xp;
        float4 v1 = *(const float4*)(xp + 4);
        bf16x8 a;
        a[0] = f2bf(v0.x); a[1] = f2bf(v0.y); a[2] = f2bf(v0.z); a[3] = f2bf(v0.w);
        a[4] = f2bf(v1.x); a[5] = f2bf(v1.y); a[6] = f2bf(v1.z); a[7] = f2bf(v1.w);
        *(bf16x8*)&ab[s * HBS + 32 * wv + q * 8] = a;
    }
    __syncthreads();

    // ---- in_proj GEMM: each wave 16 rows x 16 cols (one MFMA tile) ----
    {
        bf16x8 af[4];
        #pragma unroll
        for (int ks = 0; ks < 4; ++ks)
            af[ks] = *(const bf16x8*)&ab[s * HBS + ks * 32 + q * 8];
        acc = (f32x4){0.f, 0.f, 0.f, 0.f};
        #pragma unroll
        for (int ks = 0; ks < 4; ++ks) {
            bf16x8 b = *(const bf16x8*)&wt[colN * H + ks * 32 + q * 8];
            acc = __builtin_amdgcn_mfma_f32_16x16x32_bf16(af[ks], b, acc, 0, 0, 0);
        }
        __syncthreads();   // all x-tile reads complete before h overwrites ab
        float bi = b_in[colN];
        #pragma unroll
        for (int r = 0; r < 4; ++r) {
            h[r] = acc[r] + bi;
            ab[(4 * q + r) * HBS + colN] = f2bf(h[r]);
        }
        __syncthreads();
    }

    // degree-4 Chebyshev-truncated minimax of e^v on [-1,1]
    const float cm[KT] = {1.00004478f, 0.99730768f, 0.49919676f, 0.17734736f, 0.04379392f};

    #pragma unroll 1
    for (int layer = 0; layer < NATT; ++layer) {
        const ushort* WT = wt + (size_t)(1 + layer) * 16384;

        // ---- phase A: u = tanh(h @ W + b) ----
        bf16x8 af[4];
        #pragma unroll
        for (int ks = 0; ks < 4; ++ks)
            af[ks] = *(const bf16x8*)&ab[s * HBS + ks * 32 + q * 8];
        acc = (f32x4){0.f, 0.f, 0.f, 0.f};
        #pragma unroll
        for (int ks = 0; ks < 4; ++ks) {
            bf16x8 b = *(const bf16x8*)&WT[colN * H + ks * 32 + q * 8];
            acc = __builtin_amdgcn_mfma_f32_16x16x32_bf16(af[ks], b, acc, 0, 0, 0);
        }
        float ba = b_att[layer * H + colN];
        float u[4];
        #pragma unroll
        for (int r = 0; r < 4; ++r) u[r] = fast_tanh(acc[r] + ba);

        // ---- moments, ROW-SEQUENTIAL to bound register pressure:
        //      compute 9 moments of row r -> red16 -> LDS, then next r ----
        #pragma unroll
        for (int r = 0; r < 4; ++r) {
            float uu = u[r], hh = h[r];
            float m0 = hh;
            float p  = uu;
            float m1 = p * hh, t0 = p;
            p *= uu; float m2 = p * hh, t1 = p;
            p *= uu; float m3 = p * hh, t2 = p;
            p *= uu; float m4 = p * hh, t3 = p;
            m0 = red16(m0); m1 = red16(m1); m2 = red16(m2);
            m3 = red16(m3); m4 = red16(m4);
            t0 = red16(t0); t1 = red16(t1); t2 = red16(t2); t3 = red16(t3);
            if (s == 0) {
                float* dst = &exm[wv * EXM_CS + (4 * q + r) * 12];
                *(f32x4*)&dst[0] = (f32x4){m0, m1, m2, m3};
                *(f32x4*)&dst[4] = (f32x4){m4, t0, t1, t2};
                dst[8] = t3;
            }
        }
        __syncthreads();

        // ---- combine (lane-distributed: lane s reads copy s&7, ror:1+2+4 sums all 8)
        //      + Horner + residual + LN partial, row-sequential ----
        #pragma unroll
        for (int r = 0; r < 4; ++r) {
            const float* src = &exm[(s & 7) * EXM_CS + (4 * q + r) * 12];
            f32x4 c0 = *(const f32x4*)&src[0];
            f32x4 c1 = *(const f32x4*)&src[4];
            float c2 = src[8];
            float S0 = red8ror(c0.x) * cm[0];
            float S1 = red8ror(c0.y) * cm[1];
            float S2 = red8ror(c0.z) * cm[2];
            float S3 = red8ror(c0.w) * cm[3];
            float S4 = red8ror(c1.x) * cm[4];
            float T0 = red8ror(c1.y) * cm[1];
            float T1 = red8ror(c1.z) * cm[2];
            float T2 = red8ror(c1.w) * cm[3];
            float T3 = red8ror(c2)   * cm[4];
            float uu = u[r];
            float num = fmaf(fmaf(fmaf(fmaf(S4, uu, S3), uu, S2), uu, S1), uu, S0);
            float den = fmaf(fmaf(fmaf(fmaf(T3, uu, T2), uu, T1), uu, T0), uu,
                             128.f * 1.00004478f);
            float yy = h[r] + num * __builtin_amdgcn_rcpf(den);
            h[r] = yy;
            float lsv = red16(yy);
            float lqv = red16(yy * yy);
            if (s == 0)
                *(float2*)&exl[wv * EXL_CS + (4 * q + r) * 2] = make_float2(lsv, lqv);
        }
        __syncthreads();

        // ---- LN epilogue: normalize + refresh shared bf16 tile ----
        float g  = gamma[layer * H + colN];
        float be = beta [layer * H + colN];
        #pragma unroll
        for (int r = 0; r < 4; ++r) {
            float2 o = *(const float2*)&exl[(s & 7) * EXL_CS + (4 * q + r) * 2];
            float sm = red8ror(o.x), sq = red8ror(o.y);
            float mu = sm * (1.f / H);
            float var = sq * (1.f / H) - mu * mu;
            float inv = rsqrtf(var + EPS);
            float hn = (h[r] - mu) * inv * g + be;
            h[r] = hn;
            ab[(4 * q + r) * HBS + colN] = f2bf(hn);
        }
        __syncthreads();
    }

    // ---- final proj: wave 0 computes 16 rows x NC via one MFMA tile ----
    if (wv == 0) {
        const ushort* WC = wt + 4 * 16384;
        f32x4 facc = (f32x4){0.f, 0.f, 0.f, 0.f};
        #pragma unroll
        for (int ks = 0; ks < 4; ++ks) {
            bf16x8 a = *(const bf16x8*)&ab[s * HBS + ks * 32 + q * 8];
            bf16x8 b = *(const bf16x8*)&WC[s * H + ks * 32 + q * 8];
            facc = __builtin_amdgcn_mfma_f32_16x16x32_bf16(a, b, facc, 0, 0, 0);
        }
        if (s < NC) {
            float bc = b_c[s];
            #pragma unroll
            for (int r = 0; r < 4; ++r)
                out[(rowBase + 4 * q + r) * NC + s] = facc[r] + bc;
        }
    }
}

extern "C" void kernel_launch(void* const* d_in, const int* in_sizes, int n_in,
                              void* d_out, int out_size, void* d_ws, size_t ws_size,
                              hipStream_t stream) {
    const float* x     = (const float*)d_in[0];
    const float* W_in  = (const float*)d_in[1];
    const float* b_in  = (const float*)d_in[2];
    const float* W_att = (const float*)d_in[3];
    const float* b_att = (const float*)d_in[4];
    const float* gamma = (const float*)d_in[5];
    const float* beta  = (const float*)d_in[6];
    const float* W_c   = (const float*)d_in[7];
    const float* b_c   = (const float*)d_in[8];
    float* out  = (float*)d_out;
    ushort* wt  = (ushort*)d_ws;    // 5 mats: 4*16384 + 2048 ushorts = 136 KiB

    hipLaunchKernelGGL(prep_weights, dim3(264), dim3(256), 0, stream,
                       W_in, W_att, W_c, wt);
    hipLaunchKernelGGL(simple_attention_kernel, dim3(B_TOT / TR), dim3(512), 0, stream,
                       x, b_in, b_att, gamma, beta, b_c, wt, out);
}

// Round 6
// 100.587 us; speedup vs baseline: 1.6506x; 1.1343x over previous
//
#include <hip/hip_runtime.h>
#include <math.h>

#define B_TOT 16384
#define H     128
#define NC    10
#define NATT  3
#define TR    16      // batch rows per block; 8 waves each own a 16-wide n-tile
#define HBS   136     // bf16 LDS row stride in ushorts (272B, 16B-aligned)
#define KT    5       // degree-4 minimax of exp on [-1,1]; max err ~5.9e-4
#define EPS   1e-5f
#define EXM_S 100     // exm stride per batch-row (floats): 8 copies x 12 + 4 pad
#define EXL_S 20      // exl stride per batch-row (floats): 8 copies x 2 + 4 pad

typedef __attribute__((ext_vector_type(8))) short bf16x8;
typedef __attribute__((ext_vector_type(4))) float f32x4;

__device__ __forceinline__ ushort f2bf(float f) {
    union { float f; unsigned u; } v; v.f = f;
    unsigned r = v.u + 0x7fffu + ((v.u >> 16) & 1u);   // RNE
    return (ushort)(r >> 16);
}

// tanh(a) = 1 - 2/(e^{2a}+1); saturates correctly for |a| large
__device__ __forceinline__ float fast_tanh(float a) {
    float t = __expf(2.f * a);
    return 1.f - 2.f * __builtin_amdgcn_rcpf(t + 1.f);
}

// butterfly all-reduce over the 4 q-groups (lane bits 4,5)
__device__ __forceinline__ float redq(float v) {
    v += __shfl_xor(v, 16);
    v += __shfl_xor(v, 32);
    return v;
}

// ---- prep: wt[mat][n][k]; mat0=W_in^T, mat1..3=W_att^T, mat4=W_c^T padded to 16 rows ----
extern "C" __global__ __launch_bounds__(256)
void prep_weights(const float* __restrict__ W_in,
                  const float* __restrict__ W_att,
                  const float* __restrict__ W_c,
                  ushort* __restrict__ wt)
{
    int i = blockIdx.x * 256 + threadIdx.x;
    if (i < 65536) {
        int mat = i >> 14, idx = i & 16383;
        int k = idx >> 7, n = idx & 127;
        float v = (mat == 0) ? W_in[idx] : W_att[(mat - 1) * 16384 + idx];
        wt[mat * 16384 + n * H + k] = f2bf(v);
    } else if (i < 65536 + 2048) {
        int idx = i - 65536;
        int n = idx >> 7, k = idx & 127;
        float v = (n < NC) ? W_c[k * NC + n] : 0.f;
        wt[65536 + n * H + k] = f2bf(v);
    }
}

extern "C" __global__ __launch_bounds__(512, 6)
void simple_attention_kernel(const float* __restrict__ x,
                             const float* __restrict__ b_in,
                             const float* __restrict__ b_att,
                             const float* __restrict__ gamma,
                             const float* __restrict__ beta,
                             const float* __restrict__ b_c,
                             const ushort* __restrict__ wt,
                             float* __restrict__ out)
{
    __shared__ __align__(16) ushort ab[TR * HBS];      // bf16 h tile [batch][n]
    __shared__ __align__(16) float  exm[16 * EXM_S];   // moment exchange [batch][wave][12]
    __shared__ __align__(16) float  exl[16 * EXL_S];   // LN exchange [batch][wave][2]

    const int tid  = threadIdx.x;
    const int wv   = tid >> 6;          // wave 0..7 owns n-tile [16wv, 16wv+16)
    const int lane = tid & 63;
    const int s    = lane & 15;         // C-col: BATCH index
    const int q    = lane >> 4;
    const int nq   = 16 * wv + 4 * q;   // base n of this lane's 4 elements
    const size_t rowBase = (size_t)blockIdx.x * TR;

    float h[4];        // h[r]: element (n = nq + r, batch = s), fp32 across layers
    f32x4 acc;

    // ---- stage x tile to LDS as bf16 (waves 0..3 convert 32-col slices) ----
    if (wv < 4) {
        const float* xp = x + (rowBase + s) * H + 32 * wv + q * 8;
        float4 v0 = *(const float4*)xp;
        float4 v1 = *(const float4*)(xp + 4);
        bf16x8 a;
        a[0] = f2bf(v0.x); a[1] = f2bf(v0.y); a[2] = f2bf(v0.z); a[3] = f2bf(v0.w);
        a[4] = f2bf(v1.x); a[5] = f2bf(v1.y); a[6] = f2bf(v1.z); a[7] = f2bf(v1.w);
        *(bf16x8*)&ab[s * HBS + 32 * wv + q * 8] = a;
    }
    __syncthreads();

    // ---- in_proj GEMM, TRANSPOSED: C[n][b] = (W_in^T) @ (x^T) ----
    {
        bf16x8 bfr[4];                  // B-frag: x[b=s][k-octet] from LDS
        #pragma unroll
        for (int ks = 0; ks < 4; ++ks)
            bfr[ks] = *(const bf16x8*)&ab[s * HBS + ks * 32 + q * 8];
        acc = (f32x4){0.f, 0.f, 0.f, 0.f};
        #pragma unroll
        for (int ks = 0; ks < 4; ++ks) {
            bf16x8 a = *(const bf16x8*)&wt[(16 * wv + s) * H + ks * 32 + q * 8];
            acc = __builtin_amdgcn_mfma_f32_16x16x32_bf16(a, bfr[ks], acc, 0, 0, 0);
        }
        __syncthreads();   // all x-tile reads complete before h overwrites ab
        float4 bi4 = *(const float4*)&b_in[nq];
        uint lo, hi;
        {
            float h0 = acc[0] + bi4.x, h1 = acc[1] + bi4.y;
            float h2 = acc[2] + bi4.z, h3 = acc[3] + bi4.w;
            h[0] = h0; h[1] = h1; h[2] = h2; h[3] = h3;
            lo = (uint)f2bf(h0) | ((uint)f2bf(h1) << 16);
            hi = (uint)f2bf(h2) | ((uint)f2bf(h3) << 16);
        }
        *(uint2*)&ab[s * HBS + nq] = make_uint2(lo, hi);
        __syncthreads();
    }

    // degree-4 Chebyshev-truncated minimax of e^v on [-1,1]
    const float cm[KT] = {1.00004478f, 0.99730768f, 0.49919676f, 0.17734736f, 0.04379392f};

    #pragma unroll 1
    for (int layer = 0; layer < NATT; ++layer) {
        const ushort* WT = wt + (size_t)(1 + layer) * 16384;

        // ---- phase A GEMM (transposed): pre[n][b] = (W^T) @ (h^T) ----
        bf16x8 bfr[4];
        #pragma unroll
        for (int ks = 0; ks < 4; ++ks)
            bfr[ks] = *(const bf16x8*)&ab[s * HBS + ks * 32 + q * 8];
        acc = (f32x4){0.f, 0.f, 0.f, 0.f};
        #pragma unroll
        for (int ks = 0; ks < 4; ++ks) {
            bf16x8 a = *(const bf16x8*)&WT[(16 * wv + s) * H + ks * 32 + q * 8];
            acc = __builtin_amdgcn_mfma_f32_16x16x32_bf16(a, bfr[ks], acc, 0, 0, 0);
        }
        float4 ba4 = *(const float4*)&b_att[layer * H + nq];
        float u[4];
        u[0] = fast_tanh(acc[0] + ba4.x);
        u[1] = fast_tanh(acc[1] + ba4.y);
        u[2] = fast_tanh(acc[2] + ba4.z);
        u[3] = fast_tanh(acc[3] + ba4.w);

        // ---- in-lane moments over this lane's 4 n-elements (batch s) ----
        float m0 = 0, m1 = 0, m2 = 0, m3 = 0, m4 = 0;
        float t1 = 0, t2 = 0, t3 = 0, t4 = 0;
        #pragma unroll
        for (int r = 0; r < 4; ++r) {
            float uu = u[r], hh = h[r];
            m0 += hh;
            float p = uu;
            m1 += p * hh; t1 += p;
            p *= uu; m2 += p * hh; t2 += p;
            p *= uu; m3 += p * hh; t3 += p;
            p *= uu; m4 += p * hh; t4 += p;
        }
        // cross-q butterfly: wave-level sums over its 16 n's, all lanes get result
        m0 = redq(m0); m1 = redq(m1); m2 = redq(m2); m3 = redq(m3); m4 = redq(m4);
        t1 = redq(t1); t2 = redq(t2); t3 = redq(t3); t4 = redq(t4);
        // q-distributed write of this wave's 9 partials for batch s
        {
            float* dst = &exm[s * EXM_S + wv * 12];
            if (q == 0)      *(f32x4*)&dst[0] = (f32x4){m0, m1, m2, m3};
            else if (q == 1) *(f32x4*)&dst[4] = (f32x4){m4, t1, t2, t3};
            else if (q == 2) *(f32x4*)&dst[8] = (f32x4){t4, 0.f, 0.f, 0.f};
        }
        __syncthreads();

        // ---- cross-wave combine: lane reads copies 2q,2q+1; butterfly sums all 8 ----
        float S0, S1, S2, S3, S4, T1c, T2c, T3c, T4c;
        {
            const float* src = &exm[s * EXM_S + 24 * q];
            f32x4 a0 = *(const f32x4*)&src[0];
            f32x4 a1 = *(const f32x4*)&src[4];
            f32x4 a2 = *(const f32x4*)&src[8];
            f32x4 b0 = *(const f32x4*)&src[12];
            f32x4 b1 = *(const f32x4*)&src[16];
            f32x4 b2 = *(const f32x4*)&src[20];
            a0 += b0; a1 += b1; a2 += b2;
            S0  = redq(a0.x) * cm[0];
            S1  = redq(a0.y) * cm[1];
            S2  = redq(a0.z) * cm[2];
            S3  = redq(a0.w) * cm[3];
            S4  = redq(a1.x) * cm[4];
            T1c = redq(a1.y) * cm[1];
            T2c = redq(a1.z) * cm[2];
            T3c = redq(a1.w) * cm[3];
            T4c = redq(a2.x) * cm[4];
        }

        // ---- Horner + residual + LN partials ----
        float ls = 0.f, lq2 = 0.f;
        #pragma unroll
        for (int r = 0; r < 4; ++r) {
            float uu = u[r];
            float num = fmaf(fmaf(fmaf(fmaf(S4, uu, S3), uu, S2), uu, S1), uu, S0);
            float den = fmaf(fmaf(fmaf(fmaf(T4c, uu, T3c), uu, T2c), uu, T1c), uu,
                             128.f * 1.00004478f);   // c0 * T0
            float yy = h[r] + num * __builtin_amdgcn_rcpf(den);
            h[r] = yy;
            ls += yy; lq2 += yy * yy;
        }
        ls  = redq(ls);
        lq2 = redq(lq2);
        if (q == 0)
            *(float2*)&exl[s * EXL_S + wv * 2] = make_float2(ls, lq2);
        __syncthreads();

        // ---- LN combine + epilogue: normalize + refresh shared bf16 tile ----
        {
            f32x4 rd = *(const f32x4*)&exl[s * EXL_S + 4 * q];  // copies 2q, 2q+1
            float sm  = redq(rd.x + rd.z);
            float sq2 = redq(rd.y + rd.w);
            float mu  = sm * (1.f / H);
            float var = sq2 * (1.f / H) - mu * mu;
            float inv = rsqrtf(var + EPS);
            float4 g4  = *(const float4*)&gamma[layer * H + nq];
            float4 be4 = *(const float4*)&beta [layer * H + nq];
            float h0 = (h[0] - mu) * inv * g4.x + be4.x;
            float h1 = (h[1] - mu) * inv * g4.y + be4.y;
            float h2 = (h[2] - mu) * inv * g4.z + be4.z;
            float h3 = (h[3] - mu) * inv * g4.w + be4.w;
            h[0] = h0; h[1] = h1; h[2] = h2; h[3] = h3;
            uint lo = (uint)f2bf(h0) | ((uint)f2bf(h1) << 16);
            uint hi = (uint)f2bf(h2) | ((uint)f2bf(h3) << 16);
            *(uint2*)&ab[s * HBS + nq] = make_uint2(lo, hi);
        }
        __syncthreads();
    }

    // ---- final proj: wave 0 computes 16 rows x NC via one (untransposed) MFMA tile ----
    if (wv == 0) {
        const ushort* WC = wt + 4 * 16384;
        f32x4 facc = (f32x4){0.f, 0.f, 0.f, 0.f};
        #pragma unroll
        for (int ks = 0; ks < 4; ++ks) {
            bf16x8 a = *(const bf16x8*)&ab[s * HBS + ks * 32 + q * 8];
            bf16x8 b = *(const bf16x8*)&WC[s * H + ks * 32 + q * 8];
            facc = __builtin_amdgcn_mfma_f32_16x16x32_bf16(a, b, facc, 0, 0, 0);
        }
        if (s < NC) {
            float bc = b_c[s];
            #pragma unroll
            for (int r = 0; r < 4; ++r)
                out[(rowBase + 4 * q + r) * NC + s] = facc[r] + bc;
        }
    }
}

extern "C" void kernel_launch(void* const* d_in, const int* in_sizes, int n_in,
                              void* d_out, int out_size, void* d_ws, size_t ws_size,
                              hipStream_t stream) {
    const float* x     = (const float*)d_in[0];
    const float* W_in  = (const float*)d_in[1];
    const float* b_in  = (const float*)d_in[2];
    const float* W_att = (const float*)d_in[3];
    const float* b_att = (const float*)d_in[4];
    const float* gamma = (const float*)d_in[5];
    const float* beta  = (const float*)d_in[6];
    const float* W_c   = (const float*)d_in[7];
    const float* b_c   = (const float*)d_in[8];
    float* out  = (float*)d_out;
    ushort* wt  = (ushort*)d_ws;    // 5 mats: 4*16384 + 2048 ushorts = 136 KiB

    hipLaunchKernelGGL(prep_weights, dim3(264), dim3(256), 0, stream,
                       W_in, W_att, W_c, wt);
    hipLaunchKernelGGL(simple_attention_kernel, dim3(B_TOT / TR), dim3(512), 0, stream,
                       x, b_in, b_att, gamma, beta, b_c, wt, out);
}